// Round 1
// baseline (574.380 us; speedup 1.0000x reference)
//
#include <hip/hip_runtime.h>
#include <hip/hip_bf16.h>

#define N_NODES 100000
#define N_EDGES 1600000
#define N_ROIS  400
#define RKP     416      // 400 padded to 13*32
#define HID     128
#define N_GRAPHS 512
#define NOUT    2
#define NB1     391      // ceil(N_NODES/256)

typedef __attribute__((ext_vector_type(8))) short short8;
typedef __attribute__((ext_vector_type(4))) float f32x4;

static __device__ __forceinline__ unsigned short f2bf(float f) {
  unsigned u = __float_as_uint(f);
  u += 0x7fffu + ((u >> 16) & 1u);   // RNE
  return (unsigned short)(u >> 16);
}
static __device__ __forceinline__ float bf2f(unsigned short h) {
  return __uint_as_float(((unsigned)h) << 16);
}

// ---- degree histogram (in-degree over col) ----
__global__ void count_edges_k(const int* __restrict__ col, int* __restrict__ cnt) {
  int e = blockIdx.x * blockDim.x + threadIdx.x;
  if (e < N_EDGES) atomicAdd(&cnt[col[e]], 1);
}

// ---- scan pass 1: per-block exclusive scan + block sums; also dinv ----
__global__ void scan1_k(const int* __restrict__ cnt, int* __restrict__ offs,
                        int* __restrict__ bsum, float* __restrict__ dinv) {
  __shared__ int s[256];
  int i = blockIdx.x * 256 + threadIdx.x;
  int v = (i < N_NODES) ? cnt[i] : 0;
  if (i < N_NODES) dinv[i] = rsqrtf((float)(v + 1));   // deg includes self-loop
  s[threadIdx.x] = v;
  __syncthreads();
  for (int off = 1; off < 256; off <<= 1) {
    int t = (threadIdx.x >= off) ? s[threadIdx.x - off] : 0;
    __syncthreads();
    s[threadIdx.x] += t;
    __syncthreads();
  }
  if (i < N_NODES) offs[i] = s[threadIdx.x] - v;
  if (threadIdx.x == 255) bsum[blockIdx.x] = s[255];
}

// ---- scan pass 2: single-block scan of block sums ----
__global__ void scan2_k(int* __restrict__ bsum) {
  __shared__ int s[512];
  int v = (threadIdx.x < NB1) ? bsum[threadIdx.x] : 0;
  s[threadIdx.x] = v;
  __syncthreads();
  for (int off = 1; off < 512; off <<= 1) {
    int t = (threadIdx.x >= off) ? s[threadIdx.x - off] : 0;
    __syncthreads();
    s[threadIdx.x] += t;
    __syncthreads();
  }
  if (threadIdx.x < NB1) bsum[threadIdx.x] = s[threadIdx.x] - v;
}

// ---- scan pass 3: add block offsets; init cursor ----
__global__ void scan3_k(int* __restrict__ offs, const int* __restrict__ bsum,
                        int* __restrict__ cursor) {
  int i = blockIdx.x * 256 + threadIdx.x;
  if (i < N_NODES) {
    int o = offs[i] + bsum[blockIdx.x];
    offs[i] = o;
    cursor[i] = o;
  }
}

// ---- CSR scatter: bucket sources by target ----
__global__ void scatter_k(const int* __restrict__ row, const int* __restrict__ col,
                          int* __restrict__ cursor, int* __restrict__ csr_row) {
  int e = blockIdx.x * blockDim.x + threadIdx.x;
  if (e < N_EDGES) {
    int c = col[e];
    int p = atomicAdd(&cursor[c], 1);
    csr_row[p] = row[e];
  }
}

// ---- W [400][128] fp32 -> Wt [128][416] bf16 (transposed, zero-padded K) ----
__global__ void prep_wt_k(const float* __restrict__ W, unsigned short* __restrict__ Wt) {
  int idx = blockIdx.x * blockDim.x + threadIdx.x;
  if (idx < HID * RKP) {
    int n = idx / RKP, k = idx - n * RKP;
    float v = (k < N_ROIS) ? W[k * HID + n] : 0.f;
    Wt[idx] = f2bf(v);
  }
}

// ---- h' = (x@W) * dinv[row], bf16 MFMA, output bf16 [N][128] ----
// 16x16x32 bf16 MFMA fragment layouts (gfx950, HW-verified m89/m91):
//   A: lane holds A[m=lane&15][k=(lane>>4)*8+j], j=0..7
//   B: lane holds B[k=(lane>>4)*8+j][n=lane&15]
//   D: lane holds D[row=(lane>>4)*4+r][col=lane&15], r=0..3
__global__ __launch_bounds__(256) void gemm_k(
    const float* __restrict__ x, const unsigned short* __restrict__ Wt,
    const float* __restrict__ dinv, unsigned short* __restrict__ hp) {
  __shared__ __align__(16) short As[64][40];   // 64 rows x 32k, pad->40 (2-way bank alias: free)
  __shared__ __align__(16) short Bs[HID][40];  // 128 n-rows x 32k
  int t = threadIdx.x;
  int lane = t & 63;
  int wv = t >> 6;
  int row0 = blockIdx.x * 64;
  int mrow = lane & 15;
  int kgrp = lane >> 4;

  f32x4 acc[8];
#pragma unroll
  for (int i = 0; i < 8; ++i) acc[i] = (f32x4){0.f, 0.f, 0.f, 0.f};

  int arow = t >> 2;           // 0..63
  int akofs = (t & 3) * 8;     // 0,8,16,24
  int brow = t >> 1;           // 0..127
  int bkofs = (t & 1) * 16;    // 0,16
  int grow_a = row0 + arow;
  const float* xp = x + (size_t)grow_a * N_ROIS;

  for (int kk = 0; kk < RKP; kk += 32) {
    // stage A (fp32->bf16)
    short8 a8;
    if (grow_a < N_NODES && kk + akofs + 8 <= N_ROIS) {
      float4 f0 = *(const float4*)(xp + kk + akofs);
      float4 f1 = *(const float4*)(xp + kk + akofs + 4);
      a8[0] = (short)f2bf(f0.x); a8[1] = (short)f2bf(f0.y);
      a8[2] = (short)f2bf(f0.z); a8[3] = (short)f2bf(f0.w);
      a8[4] = (short)f2bf(f1.x); a8[5] = (short)f2bf(f1.y);
      a8[6] = (short)f2bf(f1.z); a8[7] = (short)f2bf(f1.w);
    } else {
#pragma unroll
      for (int u = 0; u < 8; ++u) {
        int k = kk + akofs + u;
        float f = (grow_a < N_NODES && k < N_ROIS) ? xp[k] : 0.f;
        a8[u] = (short)f2bf(f);
      }
    }
    *(short8*)&As[arow][akofs] = a8;
    // stage B (already bf16, copy 32B/thread)
    const short8* wp = (const short8*)(Wt + (size_t)brow * RKP + kk + bkofs);
    *(short8*)&Bs[brow][bkofs] = wp[0];
    *(short8*)&Bs[brow][bkofs + 8] = wp[1];
    __syncthreads();

    short8 af = *(const short8*)&As[wv * 16 + mrow][kgrp * 8];
#pragma unroll
    for (int nt = 0; nt < 8; ++nt) {
      short8 bf = *(const short8*)&Bs[nt * 16 + mrow][kgrp * 8];
      acc[nt] = __builtin_amdgcn_mfma_f32_16x16x32_bf16(af, bf, acc[nt], 0, 0, 0);
    }
    __syncthreads();
  }

#pragma unroll
  for (int r = 0; r < 4; ++r) {
    int grow = row0 + wv * 16 + kgrp * 4 + r;
    if (grow < N_NODES) {
      float di = dinv[grow];
      unsigned short* op = hp + (size_t)grow * HID + mrow;
#pragma unroll
      for (int nt = 0; nt < 8; ++nt) {
        op[nt * 16] = f2bf(di * acc[nt][r]);
      }
    }
  }
}

// ---- per-node aggregation (wave/node) + relu + fused max-pool via uint atomicMax ----
__global__ __launch_bounds__(256) void gather_k(
    const unsigned short* __restrict__ hp, const int* __restrict__ csr_row,
    const int* __restrict__ offs, const int* __restrict__ cnt,
    const float* __restrict__ dinv, const int* __restrict__ batch,
    const float* __restrict__ bias, unsigned int* __restrict__ pooled_bits) {
  int wave = (blockIdx.x * blockDim.x + threadIdx.x) >> 6;
  int lane = threadIdx.x & 63;
  if (wave >= N_NODES) return;
  int i = wave;
  int start = offs[i];
  int m = cnt[i];

  // self-loop term h'[i]
  unsigned int u = *(const unsigned int*)(hp + (size_t)i * HID + lane * 2);
  float ax = bf2f((unsigned short)(u & 0xffff));
  float ay = bf2f((unsigned short)(u >> 16));

  int j = 0;
  for (; j + 4 <= m; j += 4) {
    int s0 = csr_row[start + j];
    int s1 = csr_row[start + j + 1];
    int s2 = csr_row[start + j + 2];
    int s3 = csr_row[start + j + 3];
    unsigned int u0 = *(const unsigned int*)(hp + (size_t)s0 * HID + lane * 2);
    unsigned int u1 = *(const unsigned int*)(hp + (size_t)s1 * HID + lane * 2);
    unsigned int u2 = *(const unsigned int*)(hp + (size_t)s2 * HID + lane * 2);
    unsigned int u3 = *(const unsigned int*)(hp + (size_t)s3 * HID + lane * 2);
    ax += (bf2f((unsigned short)(u0 & 0xffff)) + bf2f((unsigned short)(u1 & 0xffff)))
        + (bf2f((unsigned short)(u2 & 0xffff)) + bf2f((unsigned short)(u3 & 0xffff)));
    ay += (bf2f((unsigned short)(u0 >> 16)) + bf2f((unsigned short)(u1 >> 16)))
        + (bf2f((unsigned short)(u2 >> 16)) + bf2f((unsigned short)(u3 >> 16)));
  }
  for (; j < m; ++j) {
    int s0 = csr_row[start + j];
    unsigned int u0 = *(const unsigned int*)(hp + (size_t)s0 * HID + lane * 2);
    ax += bf2f((unsigned short)(u0 & 0xffff));
    ay += bf2f((unsigned short)(u0 >> 16));
  }
  float di = dinv[i];
  float2 bb = *(const float2*)(bias + lane * 2);
  float p0 = fmaxf(fmaf(di, ax, bb.x), 0.f);
  float p1 = fmaxf(fmaf(di, ay, bb.y), 0.f);
  int g = batch[i];
  atomicMax(&pooled_bits[g * HID + lane * 2],     __float_as_uint(p0));
  atomicMax(&pooled_bits[g * HID + lane * 2 + 1], __float_as_uint(p1));
}

// ---- logits = pooled @ lin_W + lin_b ----
__global__ void logits_k(const float* __restrict__ pooled, const float* __restrict__ lin_W,
                         const float* __restrict__ lin_b, float* __restrict__ out) {
  int t = blockIdx.x * blockDim.x + threadIdx.x;
  if (t < N_GRAPHS * NOUT) {
    int g = t >> 1, o = t & 1;
    float s = lin_b[o];
    const float* pg = pooled + g * HID;
#pragma unroll 8
    for (int k = 0; k < HID; ++k) s = fmaf(pg[k], lin_W[k * NOUT + o], s);
    out[t] = s;
  }
}

extern "C" void kernel_launch(void* const* d_in, const int* in_sizes, int n_in,
                              void* d_out, int out_size, void* d_ws, size_t ws_size,
                              hipStream_t stream) {
  (void)in_sizes; (void)n_in; (void)ws_size;
  const float* x     = (const float*)d_in[0];
  const int*   ei    = (const int*)d_in[1];
  const int*   row   = ei;             // sources
  const int*   col   = ei + N_EDGES;   // targets
  const int*   batch = (const int*)d_in[2];
  const float* W     = (const float*)d_in[3];
  const float* b     = (const float*)d_in[4];
  const float* lin_W = (const float*)d_in[5];
  const float* lin_b = (const float*)d_in[6];
  float* out = (float*)d_out;

  char* ws = (char*)d_ws;
  int*   cnt     = (int*)(ws + 0);              // 400,000 B
  float* dinv    = (float*)(ws + 400000);       // 400,000 B
  int*   offs    = (int*)(ws + 800000);         // 400,000 B
  int*   cursor  = (int*)(ws + 1200000);        // 400,000 B
  int*   csr_row = (int*)(ws + 1600000);        // 6,400,000 B
  int*   bsum    = (int*)(ws + 8000000);        // 2,048 B
  unsigned short* Wt = (unsigned short*)(ws + 8002048);   // 106,496 B
  unsigned short* hp = (unsigned short*)(ws + 8108544);   // 25,600,000 B

  hipMemsetAsync(cnt, 0, N_NODES * sizeof(int), stream);
  hipMemsetAsync(d_out, 0, (size_t)out_size * sizeof(float), stream);

  count_edges_k<<<(N_EDGES + 255) / 256, 256, 0, stream>>>(col, cnt);
  scan1_k<<<NB1, 256, 0, stream>>>(cnt, offs, bsum, dinv);
  scan2_k<<<1, 512, 0, stream>>>(bsum);
  scan3_k<<<NB1, 256, 0, stream>>>(offs, bsum, cursor);
  scatter_k<<<(N_EDGES + 255) / 256, 256, 0, stream>>>(row, col, cursor, csr_row);
  prep_wt_k<<<(HID * RKP + 255) / 256, 256, 0, stream>>>(W, Wt);
  gemm_k<<<(N_NODES + 63) / 64, 256, 0, stream>>>(x, Wt, dinv, hp);
  gather_k<<<(N_NODES * 64) / 256, 256, 0, stream>>>(
      hp, csr_row, offs, cnt, dinv, batch, b,
      (unsigned int*)(out + N_GRAPHS * NOUT));
  logits_k<<<(N_GRAPHS * NOUT + 255) / 256, 256, 0, stream>>>(
      out + N_GRAPHS * NOUT, lin_W, lin_b, out);
}

// Round 2
// 493.242 us; speedup vs baseline: 1.1645x; 1.1645x over previous
//
#include <hip/hip_runtime.h>
#include <hip/hip_bf16.h>

#define N_NODES 100000
#define N_EDGES 1600000
#define N_ROIS  400
#define RKP     416      // 400 padded to 13*32
#define HID     128
#define N_GRAPHS 512
#define NOUT    2
#define NB1     391      // ceil(N_NODES/256)
#define NBUCK   391      // ceil(N_NODES/256), bucket = node >> 8
#define ECH     4096     // edges per bucket_k block

typedef __attribute__((ext_vector_type(8))) short short8;
typedef __attribute__((ext_vector_type(4))) float f32x4;

static __device__ __forceinline__ unsigned short f2bf(float f) {
  unsigned u = __float_as_uint(f);
  u += 0x7fffu + ((u >> 16) & 1u);   // RNE
  return (unsigned short)(u >> 16);
}
static __device__ __forceinline__ float bf2f(unsigned short h) {
  return __uint_as_float(((unsigned)h) << 16);
}

// ---- degree histogram (in-degree over col) ----
__global__ void count_edges_k(const int* __restrict__ col, int* __restrict__ cnt) {
  int e = blockIdx.x * blockDim.x + threadIdx.x;
  if (e < N_EDGES) atomicAdd(&cnt[col[e]], 1);
}

// ---- scan pass 1: per-block exclusive scan + block sums; also dinv ----
__global__ void scan1_k(const int* __restrict__ cnt, int* __restrict__ offs,
                        int* __restrict__ bsum, float* __restrict__ dinv) {
  __shared__ int s[256];
  int i = blockIdx.x * 256 + threadIdx.x;
  int v = (i < N_NODES) ? cnt[i] : 0;
  if (i < N_NODES) dinv[i] = rsqrtf((float)(v + 1));   // deg includes self-loop
  s[threadIdx.x] = v;
  __syncthreads();
  for (int off = 1; off < 256; off <<= 1) {
    int t = (threadIdx.x >= off) ? s[threadIdx.x - off] : 0;
    __syncthreads();
    s[threadIdx.x] += t;
    __syncthreads();
  }
  if (i < N_NODES) offs[i] = s[threadIdx.x] - v;
  if (threadIdx.x == 255) bsum[blockIdx.x] = s[255];
}

// ---- scan pass 2: single-block scan of block sums ----
__global__ void scan2_k(int* __restrict__ bsum) {
  __shared__ int s[512];
  int v = (threadIdx.x < NB1) ? bsum[threadIdx.x] : 0;
  s[threadIdx.x] = v;
  __syncthreads();
  for (int off = 1; off < 512; off <<= 1) {
    int t = (threadIdx.x >= off) ? s[threadIdx.x - off] : 0;
    __syncthreads();
    s[threadIdx.x] += t;
    __syncthreads();
  }
  if (threadIdx.x < NB1) bsum[threadIdx.x] = s[threadIdx.x] - v;
}

// ---- scan pass 3: add block offsets; init per-bucket cursor ----
__global__ void scan3_k(int* __restrict__ offs, const int* __restrict__ bsum,
                        int* __restrict__ bcur) {
  int i = blockIdx.x * 256 + threadIdx.x;
  if (i < N_NODES) {
    int o = offs[i] + bsum[blockIdx.x];
    offs[i] = o;
    if ((i & 255) == 0) bcur[i >> 8] = o;   // bucket frontier = offs[b*256]
  }
}

// ---- phase 1: bucket edges by col>>8 into packed (row<<8 | col&255) ----
__global__ __launch_bounds__(256) void bucket_k(
    const int* __restrict__ row, const int* __restrict__ col,
    int* __restrict__ bcur, unsigned int* __restrict__ pairs) {
  __shared__ int hist[NBUCK];
  __shared__ int base[NBUCK];
  int t = threadIdx.x;
  for (int b = t; b < NBUCK; b += 256) hist[b] = 0;
  __syncthreads();
  int e0 = blockIdx.x * ECH;
  unsigned int pk[16];
  int bk[16], rk[16];
#pragma unroll
  for (int i = 0; i < 16; ++i) {
    int e = e0 + t + i * 256;
    if (e < N_EDGES) {
      int r = row[e], c = col[e];
      bk[i] = c >> 8;
      pk[i] = ((unsigned)r << 8) | (unsigned)(c & 255);
      rk[i] = atomicAdd(&hist[bk[i]], 1);   // LDS atomic: local rank
    } else bk[i] = -1;
  }
  __syncthreads();
  for (int b = t; b < NBUCK; b += 256)
    base[b] = (hist[b] > 0) ? atomicAdd(&bcur[b], hist[b]) : 0;
  __syncthreads();
#pragma unroll
  for (int i = 0; i < 16; ++i)
    if (bk[i] >= 0) pairs[base[bk[i]] + rk[i]] = pk[i];
}

// ---- phase 2: one block per bucket; LDS per-node cursors; scatter within 16KB window ----
__global__ __launch_bounds__(256) void csr_build_k(
    const unsigned int* __restrict__ pairs, const int* __restrict__ offs,
    int* __restrict__ csr_row) {
  __shared__ int lcur[256];
  int b = blockIdx.x;
  int t = threadIdx.x;
  int node = b * 256 + t;
  lcur[t] = (node < N_NODES) ? offs[node] : 0;
  int rstart = offs[b * 256];   // b*256 < N_NODES always (max 99840)
  int rend = (b + 1 < NBUCK) ? offs[(b + 1) * 256] : N_EDGES;
  __syncthreads();
  for (int j = rstart + t; j < rend; j += 256) {
    unsigned int e = pairs[j];
    int cl = (int)(e & 255u);
    int r = (int)(e >> 8);
    int pos = atomicAdd(&lcur[cl], 1);     // LDS atomic
    csr_row[pos] = r;                      // 4B scatter within bucket's ~16KB window
  }
}

// ---- W [400][128] fp32 -> Wt [128][416] bf16 (transposed, zero-padded K) ----
__global__ void prep_wt_k(const float* __restrict__ W, unsigned short* __restrict__ Wt) {
  int idx = blockIdx.x * blockDim.x + threadIdx.x;
  if (idx < HID * RKP) {
    int n = idx / RKP, k = idx - n * RKP;
    float v = (k < N_ROIS) ? W[k * HID + n] : 0.f;
    Wt[idx] = f2bf(v);
  }
}

// ---- h' = (x@W) * dinv[row], bf16 MFMA, output bf16 [N][128] ----
__global__ __launch_bounds__(256) void gemm_k(
    const float* __restrict__ x, const unsigned short* __restrict__ Wt,
    const float* __restrict__ dinv, unsigned short* __restrict__ hp) {
  __shared__ __align__(16) short As[64][40];
  __shared__ __align__(16) short Bs[HID][40];
  int t = threadIdx.x;
  int lane = t & 63;
  int wv = t >> 6;
  int row0 = blockIdx.x * 64;
  int mrow = lane & 15;
  int kgrp = lane >> 4;

  f32x4 acc[8];
#pragma unroll
  for (int i = 0; i < 8; ++i) acc[i] = (f32x4){0.f, 0.f, 0.f, 0.f};

  int arow = t >> 2;
  int akofs = (t & 3) * 8;
  int brow = t >> 1;
  int bkofs = (t & 1) * 16;
  int grow_a = row0 + arow;
  const float* xp = x + (size_t)grow_a * N_ROIS;

  for (int kk = 0; kk < RKP; kk += 32) {
    short8 a8;
    if (grow_a < N_NODES && kk + akofs + 8 <= N_ROIS) {
      float4 f0 = *(const float4*)(xp + kk + akofs);
      float4 f1 = *(const float4*)(xp + kk + akofs + 4);
      a8[0] = (short)f2bf(f0.x); a8[1] = (short)f2bf(f0.y);
      a8[2] = (short)f2bf(f0.z); a8[3] = (short)f2bf(f0.w);
      a8[4] = (short)f2bf(f1.x); a8[5] = (short)f2bf(f1.y);
      a8[6] = (short)f2bf(f1.z); a8[7] = (short)f2bf(f1.w);
    } else {
#pragma unroll
      for (int u = 0; u < 8; ++u) {
        int k = kk + akofs + u;
        float f = (grow_a < N_NODES && k < N_ROIS) ? xp[k] : 0.f;
        a8[u] = (short)f2bf(f);
      }
    }
    *(short8*)&As[arow][akofs] = a8;
    const short8* wp = (const short8*)(Wt + (size_t)brow * RKP + kk + bkofs);
    *(short8*)&Bs[brow][bkofs] = wp[0];
    *(short8*)&Bs[brow][bkofs + 8] = wp[1];
    __syncthreads();

    short8 af = *(const short8*)&As[wv * 16 + mrow][kgrp * 8];
#pragma unroll
    for (int nt = 0; nt < 8; ++nt) {
      short8 bf = *(const short8*)&Bs[nt * 16 + mrow][kgrp * 8];
      acc[nt] = __builtin_amdgcn_mfma_f32_16x16x32_bf16(af, bf, acc[nt], 0, 0, 0);
    }
    __syncthreads();
  }

#pragma unroll
  for (int r = 0; r < 4; ++r) {
    int grow = row0 + wv * 16 + kgrp * 4 + r;
    if (grow < N_NODES) {
      float di = dinv[grow];
      unsigned short* op = hp + (size_t)grow * HID + mrow;
#pragma unroll
      for (int nt = 0; nt < 8; ++nt) {
        op[nt * 16] = f2bf(di * acc[nt][r]);
      }
    }
  }
}

// ---- per-node aggregation (wave/node) + relu + fused max-pool via uint atomicMax ----
__global__ __launch_bounds__(256) void gather_k(
    const unsigned short* __restrict__ hp, const int* __restrict__ csr_row,
    const int* __restrict__ offs, const int* __restrict__ cnt,
    const float* __restrict__ dinv, const int* __restrict__ batch,
    const float* __restrict__ bias, unsigned int* __restrict__ pooled_bits) {
  int wave = (blockIdx.x * blockDim.x + threadIdx.x) >> 6;
  int lane = threadIdx.x & 63;
  if (wave >= N_NODES) return;
  int i = wave;
  int start = offs[i];
  int m = cnt[i];

  unsigned int u = *(const unsigned int*)(hp + (size_t)i * HID + lane * 2);
  float ax = bf2f((unsigned short)(u & 0xffff));
  float ay = bf2f((unsigned short)(u >> 16));

  int j = 0;
  for (; j + 4 <= m; j += 4) {
    int s0 = csr_row[start + j];
    int s1 = csr_row[start + j + 1];
    int s2 = csr_row[start + j + 2];
    int s3 = csr_row[start + j + 3];
    unsigned int u0 = *(const unsigned int*)(hp + (size_t)s0 * HID + lane * 2);
    unsigned int u1 = *(const unsigned int*)(hp + (size_t)s1 * HID + lane * 2);
    unsigned int u2 = *(const unsigned int*)(hp + (size_t)s2 * HID + lane * 2);
    unsigned int u3 = *(const unsigned int*)(hp + (size_t)s3 * HID + lane * 2);
    ax += (bf2f((unsigned short)(u0 & 0xffff)) + bf2f((unsigned short)(u1 & 0xffff)))
        + (bf2f((unsigned short)(u2 & 0xffff)) + bf2f((unsigned short)(u3 & 0xffff)));
    ay += (bf2f((unsigned short)(u0 >> 16)) + bf2f((unsigned short)(u1 >> 16)))
        + (bf2f((unsigned short)(u2 >> 16)) + bf2f((unsigned short)(u3 >> 16)));
  }
  for (; j < m; ++j) {
    int s0 = csr_row[start + j];
    unsigned int u0 = *(const unsigned int*)(hp + (size_t)s0 * HID + lane * 2);
    ax += bf2f((unsigned short)(u0 & 0xffff));
    ay += bf2f((unsigned short)(u0 >> 16));
  }
  float di = dinv[i];
  float2 bb = *(const float2*)(bias + lane * 2);
  float p0 = fmaxf(fmaf(di, ax, bb.x), 0.f);
  float p1 = fmaxf(fmaf(di, ay, bb.y), 0.f);
  int g = batch[i];
  atomicMax(&pooled_bits[g * HID + lane * 2],     __float_as_uint(p0));
  atomicMax(&pooled_bits[g * HID + lane * 2 + 1], __float_as_uint(p1));
}

// ---- logits = pooled @ lin_W + lin_b ----
__global__ void logits_k(const float* __restrict__ pooled, const float* __restrict__ lin_W,
                         const float* __restrict__ lin_b, float* __restrict__ out) {
  int t = blockIdx.x * blockDim.x + threadIdx.x;
  if (t < N_GRAPHS * NOUT) {
    int g = t >> 1, o = t & 1;
    float s = lin_b[o];
    const float* pg = pooled + g * HID;
#pragma unroll 8
    for (int k = 0; k < HID; ++k) s = fmaf(pg[k], lin_W[k * NOUT + o], s);
    out[t] = s;
  }
}

extern "C" void kernel_launch(void* const* d_in, const int* in_sizes, int n_in,
                              void* d_out, int out_size, void* d_ws, size_t ws_size,
                              hipStream_t stream) {
  (void)in_sizes; (void)n_in; (void)ws_size;
  const float* x     = (const float*)d_in[0];
  const int*   ei    = (const int*)d_in[1];
  const int*   row   = ei;             // sources
  const int*   col   = ei + N_EDGES;   // targets
  const int*   batch = (const int*)d_in[2];
  const float* W     = (const float*)d_in[3];
  const float* b     = (const float*)d_in[4];
  const float* lin_W = (const float*)d_in[5];
  const float* lin_b = (const float*)d_in[6];
  float* out = (float*)d_out;

  char* ws = (char*)d_ws;
  int*   cnt     = (int*)(ws + 0);              // 400,000 B
  float* dinv    = (float*)(ws + 400000);       // 400,000 B
  int*   offs    = (int*)(ws + 800000);         // 400,000 B
  int*   bcur    = (int*)(ws + 1200000);        // 1,564 B (bucket cursors)
  int*   csr_row = (int*)(ws + 1600000);        // 6,400,000 B
  int*   bsum    = (int*)(ws + 8000000);        // 2,048 B
  unsigned short* Wt = (unsigned short*)(ws + 8002048);   // 106,496 B
  unsigned short* hp = (unsigned short*)(ws + 8108544);   // 25,600,000 B
  unsigned int* pairs = (unsigned int*)(ws + 33708544);   // 6,400,000 B

  hipMemsetAsync(cnt, 0, N_NODES * sizeof(int), stream);
  hipMemsetAsync(d_out, 0, (size_t)out_size * sizeof(float), stream);

  count_edges_k<<<(N_EDGES + 255) / 256, 256, 0, stream>>>(col, cnt);
  scan1_k<<<NB1, 256, 0, stream>>>(cnt, offs, bsum, dinv);
  scan2_k<<<1, 512, 0, stream>>>(bsum);
  scan3_k<<<NB1, 256, 0, stream>>>(offs, bsum, bcur);
  bucket_k<<<(N_EDGES + ECH - 1) / ECH, 256, 0, stream>>>(row, col, bcur, pairs);
  csr_build_k<<<NBUCK, 256, 0, stream>>>(pairs, offs, csr_row);
  prep_wt_k<<<(HID * RKP + 255) / 256, 256, 0, stream>>>(W, Wt);
  gemm_k<<<(N_NODES + 63) / 64, 256, 0, stream>>>(x, Wt, dinv, hp);
  gather_k<<<(N_NODES * 64) / 256, 256, 0, stream>>>(
      hp, csr_row, offs, cnt, dinv, batch, b,
      (unsigned int*)(out + N_GRAPHS * NOUT));
  logits_k<<<(N_GRAPHS * NOUT + 255) / 256, 256, 0, stream>>>(
      out + N_GRAPHS * NOUT, lin_W, lin_b, out);
}

// Round 3
// 391.410 us; speedup vs baseline: 1.4675x; 1.2602x over previous
//
#include <hip/hip_runtime.h>
#include <hip/hip_bf16.h>

#define N_NODES 100000
#define N_EDGES 1600000
#define N_ROIS  400
#define RKP     416      // 400 padded to 13*32
#define HID     128
#define N_GRAPHS 512
#define NOUT    2
#define NBUCK   391      // ceil(N_NODES/256), bucket = node >> 8
#define BCAP    8192     // per-bucket edge capacity (mean 4092, sigma 64 -> 64 sigma margin)
#define ECH     4096     // edges per bucket_k block
#define NPW     16       // nodes per gather wave (batch sorted; ~195 nodes/graph)

typedef __attribute__((ext_vector_type(8))) short short8;
typedef __attribute__((ext_vector_type(4))) float f32x4;

static __device__ __forceinline__ unsigned short f2bf(float f) {
  unsigned u = __float_as_uint(f);
  u += 0x7fffu + ((u >> 16) & 1u);   // RNE
  return (unsigned short)(u >> 16);
}
static __device__ __forceinline__ float bf2f(unsigned short h) {
  return __uint_as_float(((unsigned)h) << 16);
}

// ---- single-pass bucket append: pairs[b*BCAP + rank] = (row<<8 | col&255) ----
__global__ __launch_bounds__(256) void bucket_k(
    const int* __restrict__ row, const int* __restrict__ col,
    int* __restrict__ bcnt, unsigned int* __restrict__ pairs) {
  __shared__ int hist[NBUCK];
  __shared__ int base[NBUCK];
  int t = threadIdx.x;
  for (int b = t; b < NBUCK; b += 256) hist[b] = 0;
  __syncthreads();
  int e0 = blockIdx.x * ECH;
  unsigned int pk[16];
  int bk[16], rk[16];
#pragma unroll
  for (int i = 0; i < 16; ++i) {
    int e = e0 + t + i * 256;
    if (e < N_EDGES) {
      int r = row[e], c = col[e];
      bk[i] = c >> 8;
      pk[i] = ((unsigned)r << 8) | (unsigned)(c & 255);
      rk[i] = atomicAdd(&hist[bk[i]], 1);   // LDS atomic: local rank
    } else bk[i] = -1;
  }
  __syncthreads();
  for (int b = t; b < NBUCK; b += 256)
    base[b] = (hist[b] > 0) ? atomicAdd(&bcnt[b], hist[b]) : 0;
  __syncthreads();
#pragma unroll
  for (int i = 0; i < 16; ++i)
    if (bk[i] >= 0) {
      int p = base[bk[i]] + rk[i];
      if (p < BCAP) pairs[(size_t)bk[i] * BCAP + p] = pk[i];
    }
}

// ---- per-bucket CSR build entirely in LDS: counts, offsets, dinv, scatter ----
__global__ __launch_bounds__(256) void csr_build_k(
    const unsigned int* __restrict__ pairs, const int* __restrict__ bcnt,
    int* __restrict__ csr_row, int* __restrict__ offs, int* __restrict__ cnt,
    float* __restrict__ dinv) {
  __shared__ unsigned int ep[BCAP];
  __shared__ int h[256];
  __shared__ int sc[256];
  __shared__ int cur[256];
  int b = blockIdx.x;
  int t = threadIdx.x;
  int m = min(bcnt[b], BCAP);
  size_t base = (size_t)b * BCAP;
  for (int j = t; j < m; j += 256) ep[j] = pairs[base + j];
  h[t] = 0;
  __syncthreads();
  for (int j = t; j < m; j += 256) atomicAdd(&h[ep[j] & 255u], 1);
  __syncthreads();
  int myc = h[t];
  sc[t] = myc;
  __syncthreads();
  for (int off = 1; off < 256; off <<= 1) {
    int v = (t >= off) ? sc[t - off] : 0;
    __syncthreads();
    sc[t] += v;
    __syncthreads();
  }
  int loff = sc[t] - myc;     // exclusive scan
  cur[t] = loff;
  int node = b * 256 + t;
  if (node < N_NODES) {
    cnt[node] = myc;
    offs[node] = (int)base + loff;
    dinv[node] = rsqrtf((float)(myc + 1));
  }
  __syncthreads();
  for (int j = t; j < m; j += 256) {
    unsigned int e = ep[j];
    int pos = atomicAdd(&cur[e & 255u], 1);   // LDS atomic
    csr_row[base + pos] = (int)(e >> 8);
  }
}

// ---- W [400][128] fp32 -> Wt [128][416] bf16 (transposed, zero-padded K) ----
__global__ void prep_wt_k(const float* __restrict__ W, unsigned short* __restrict__ Wt) {
  int idx = blockIdx.x * blockDim.x + threadIdx.x;
  if (idx < HID * RKP) {
    int n = idx / RKP, k = idx - n * RKP;
    float v = (k < N_ROIS) ? W[k * HID + n] : 0.f;
    Wt[idx] = f2bf(v);
  }
}

// ---- h' = (x@W) * dinv[row], bf16 MFMA, output bf16 [N][128] ----
__global__ __launch_bounds__(256) void gemm_k(
    const float* __restrict__ x, const unsigned short* __restrict__ Wt,
    const float* __restrict__ dinv, unsigned short* __restrict__ hp) {
  __shared__ __align__(16) short As[64][40];
  __shared__ __align__(16) short Bs[HID][40];
  int t = threadIdx.x;
  int lane = t & 63;
  int wv = t >> 6;
  int row0 = blockIdx.x * 64;
  int mrow = lane & 15;
  int kgrp = lane >> 4;

  f32x4 acc[8];
#pragma unroll
  for (int i = 0; i < 8; ++i) acc[i] = (f32x4){0.f, 0.f, 0.f, 0.f};

  int arow = t >> 2;
  int akofs = (t & 3) * 8;
  int brow = t >> 1;
  int bkofs = (t & 1) * 16;
  int grow_a = row0 + arow;
  const float* xp = x + (size_t)grow_a * N_ROIS;

  for (int kk = 0; kk < RKP; kk += 32) {
    short8 a8;
    if (grow_a < N_NODES && kk + akofs + 8 <= N_ROIS) {
      float4 f0 = *(const float4*)(xp + kk + akofs);
      float4 f1 = *(const float4*)(xp + kk + akofs + 4);
      a8[0] = (short)f2bf(f0.x); a8[1] = (short)f2bf(f0.y);
      a8[2] = (short)f2bf(f0.z); a8[3] = (short)f2bf(f0.w);
      a8[4] = (short)f2bf(f1.x); a8[5] = (short)f2bf(f1.y);
      a8[6] = (short)f2bf(f1.z); a8[7] = (short)f2bf(f1.w);
    } else {
#pragma unroll
      for (int u = 0; u < 8; ++u) {
        int k = kk + akofs + u;
        float f = (grow_a < N_NODES && k < N_ROIS) ? xp[k] : 0.f;
        a8[u] = (short)f2bf(f);
      }
    }
    *(short8*)&As[arow][akofs] = a8;
    const short8* wp = (const short8*)(Wt + (size_t)brow * RKP + kk + bkofs);
    *(short8*)&Bs[brow][bkofs] = wp[0];
    *(short8*)&Bs[brow][bkofs + 8] = wp[1];
    __syncthreads();

    short8 af = *(const short8*)&As[wv * 16 + mrow][kgrp * 8];
#pragma unroll
    for (int nt = 0; nt < 8; ++nt) {
      short8 bf = *(const short8*)&Bs[nt * 16 + mrow][kgrp * 8];
      acc[nt] = __builtin_amdgcn_mfma_f32_16x16x32_bf16(af, bf, acc[nt], 0, 0, 0);
    }
    __syncthreads();
  }

#pragma unroll
  for (int r = 0; r < 4; ++r) {
    int grow = row0 + wv * 16 + kgrp * 4 + r;
    if (grow < N_NODES) {
      float di = dinv[grow];
      unsigned short* op = hp + (size_t)grow * HID + mrow;
#pragma unroll
      for (int nt = 0; nt < 8; ++nt) {
        op[nt * 16] = f2bf(di * acc[nt][r]);
      }
    }
  }
}

// ---- aggregation: wave handles NPW consecutive nodes; pooled max kept in
// registers, flushed on (wave-uniform) graph-id change -> ~16x fewer atomics ----
__global__ __launch_bounds__(256) void gather_k(
    const unsigned short* __restrict__ hp, const int* __restrict__ csr_row,
    const int* __restrict__ offs, const int* __restrict__ cnt,
    const float* __restrict__ dinv, const int* __restrict__ batch,
    const float* __restrict__ bias, unsigned int* __restrict__ pooled_bits) {
  int wave = (blockIdx.x * blockDim.x + threadIdx.x) >> 6;
  int lane = threadIdx.x & 63;
  int n0 = wave * NPW;
  if (n0 >= N_NODES) return;
  int nend = min(n0 + NPW, N_NODES);
  float2 bb = *(const float2*)(bias + lane * 2);
  float rm0 = 0.f, rm1 = 0.f;      // relu >= 0, pooled zero-init -> 0 is identity
  int cur_g = batch[n0];

  for (int i = n0; i < nend; ++i) {
    int start = offs[i];
    int m = cnt[i];
    unsigned int u = *(const unsigned int*)(hp + (size_t)i * HID + lane * 2);
    float ax = bf2f((unsigned short)(u & 0xffff));
    float ay = bf2f((unsigned short)(u >> 16));
    int j = 0;
    for (; j + 4 <= m; j += 4) {
      int s0 = csr_row[start + j];
      int s1 = csr_row[start + j + 1];
      int s2 = csr_row[start + j + 2];
      int s3 = csr_row[start + j + 3];
      unsigned int u0 = *(const unsigned int*)(hp + (size_t)s0 * HID + lane * 2);
      unsigned int u1 = *(const unsigned int*)(hp + (size_t)s1 * HID + lane * 2);
      unsigned int u2 = *(const unsigned int*)(hp + (size_t)s2 * HID + lane * 2);
      unsigned int u3 = *(const unsigned int*)(hp + (size_t)s3 * HID + lane * 2);
      ax += (bf2f((unsigned short)(u0 & 0xffff)) + bf2f((unsigned short)(u1 & 0xffff)))
          + (bf2f((unsigned short)(u2 & 0xffff)) + bf2f((unsigned short)(u3 & 0xffff)));
      ay += (bf2f((unsigned short)(u0 >> 16)) + bf2f((unsigned short)(u1 >> 16)))
          + (bf2f((unsigned short)(u2 >> 16)) + bf2f((unsigned short)(u3 >> 16)));
    }
    for (; j < m; ++j) {
      int s0 = csr_row[start + j];
      unsigned int u0 = *(const unsigned int*)(hp + (size_t)s0 * HID + lane * 2);
      ax += bf2f((unsigned short)(u0 & 0xffff));
      ay += bf2f((unsigned short)(u0 >> 16));
    }
    float di = dinv[i];
    float p0 = fmaxf(fmaf(di, ax, bb.x), 0.f);
    float p1 = fmaxf(fmaf(di, ay, bb.y), 0.f);
    int g = batch[i];
    if (g != cur_g) {              // wave-uniform branch (all lanes share i)
      atomicMax(&pooled_bits[cur_g * HID + lane * 2],     __float_as_uint(rm0));
      atomicMax(&pooled_bits[cur_g * HID + lane * 2 + 1], __float_as_uint(rm1));
      rm0 = 0.f; rm1 = 0.f;
      cur_g = g;
    }
    rm0 = fmaxf(rm0, p0);
    rm1 = fmaxf(rm1, p1);
  }
  atomicMax(&pooled_bits[cur_g * HID + lane * 2],     __float_as_uint(rm0));
  atomicMax(&pooled_bits[cur_g * HID + lane * 2 + 1], __float_as_uint(rm1));
}

// ---- logits = pooled @ lin_W + lin_b ----
__global__ void logits_k(const float* __restrict__ pooled, const float* __restrict__ lin_W,
                         const float* __restrict__ lin_b, float* __restrict__ out) {
  int t = blockIdx.x * blockDim.x + threadIdx.x;
  if (t < N_GRAPHS * NOUT) {
    int g = t >> 1, o = t & 1;
    float s = lin_b[o];
    const float* pg = pooled + g * HID;
#pragma unroll 8
    for (int k = 0; k < HID; ++k) s = fmaf(pg[k], lin_W[k * NOUT + o], s);
    out[t] = s;
  }
}

extern "C" void kernel_launch(void* const* d_in, const int* in_sizes, int n_in,
                              void* d_out, int out_size, void* d_ws, size_t ws_size,
                              hipStream_t stream) {
  (void)in_sizes; (void)n_in; (void)ws_size;
  const float* x     = (const float*)d_in[0];
  const int*   ei    = (const int*)d_in[1];
  const int*   row   = ei;             // sources
  const int*   col   = ei + N_EDGES;   // targets
  const int*   batch = (const int*)d_in[2];
  const float* W     = (const float*)d_in[3];
  const float* b     = (const float*)d_in[4];
  const float* lin_W = (const float*)d_in[5];
  const float* lin_b = (const float*)d_in[6];
  float* out = (float*)d_out;

  // workspace layout (39.73 MB total; pairs dead after csr_build_k -> hp aliases it)
  char* ws = (char*)d_ws;
  int*   bcnt    = (int*)(ws + 0);               //   4,096 B (391 used)
  int*   offs    = (int*)(ws + 4096);            // 400,000 B
  int*   cnt     = (int*)(ws + 404096);          // 400,000 B
  float* dinv    = (float*)(ws + 804096);        // 400,000 B
  unsigned short* Wt = (unsigned short*)(ws + 1204096);   // 106,496 B
  int*   csr_row = (int*)(ws + 1310720);         // 391*8192*4 = 12,812,288 B
  unsigned int* pairs = (unsigned int*)(ws + 14123008);   // 12,812,288 B
  unsigned short* hp  = (unsigned short*)(ws + 14123008); // 25,600,000 B (aliases pairs)

  hipMemsetAsync(bcnt, 0, NBUCK * sizeof(int), stream);
  hipMemsetAsync(d_out, 0, (size_t)out_size * sizeof(float), stream);

  bucket_k<<<(N_EDGES + ECH - 1) / ECH, 256, 0, stream>>>(row, col, bcnt, pairs);
  csr_build_k<<<NBUCK, 256, 0, stream>>>(pairs, bcnt, csr_row, offs, cnt, dinv);
  prep_wt_k<<<(HID * RKP + 255) / 256, 256, 0, stream>>>(W, Wt);
  gemm_k<<<(N_NODES + 63) / 64, 256, 0, stream>>>(x, Wt, dinv, hp);
  {
    int waves = (N_NODES + NPW - 1) / NPW;             // 6250
    int blocks = (waves * 64 + 255) / 256;             // 1563
    gather_k<<<blocks, 256, 0, stream>>>(
        hp, csr_row, offs, cnt, dinv, batch, b,
        (unsigned int*)(out + N_GRAPHS * NOUT));
  }
  logits_k<<<(N_GRAPHS * NOUT + 255) / 256, 256, 0, stream>>>(
      out + N_GRAPHS * NOUT, lin_W, lin_b, out);
}